// Round 1
// baseline (363.330 us; speedup 1.0000x reference)
//
#include <hip/hip_runtime.h>
#include <hip/hip_fp16.h>

#define N_NODES 100000
#define N_EDGES 1600000
#define E_TOT   (N_EDGES + N_NODES)   // 1,700,000 incl. self-loops
#define NEG_SLOPE 0.2f
#define PART_EPB 4096                 // edges per partition block
#define BSTRIDE 18432                 // slots per bucket region (mean 17408 + 7.8 sigma)
#define NGEMM (N_NODES / 32)          // 3125 gemm blocks
#define NPART ((E_TOT + PART_EPB - 1) / PART_EPB)   // 416 partition blocks

using f16x8 = __attribute__((ext_vector_type(8))) _Float16;
using f32x4 = __attribute__((ext_vector_type(4))) float;
union H8 { f16x8 v; _Float16 h[8]; };

// ---------------------------------------------------------------------------
// Merged kernel: blocks < NGEMM do the layer-1 GEMM via MFMA (fp16 in, fp32
// acc). Blocks >= NGEMM do the edge bucket-partition (zero data dependency
// between the roles -> one dispatch, overlapped).
// ---------------------------------------------------------------------------
__global__ __launch_bounds__(256)
void k_gemm1_part(const float* __restrict__ x, const float* __restrict__ W1,
                  const float* __restrict__ a_src1, const float* __restrict__ a_dst1,
                  const int* __restrict__ ei, int* __restrict__ bcnt, int* __restrict__ pairs,
                  __half* __restrict__ xw1h, float* __restrict__ al1, float* __restrict__ ar1) {
    __shared__ int lcnt[128];
    __shared__ int lbase[128];
    const int t = threadIdx.x;

    if (blockIdx.x >= NGEMM) {
        // ===== edge-partition role =====
        const int base = ((int)blockIdx.x - NGEMM) * PART_EPB;
        if (t < 128) lcnt[t] = 0;
        __syncthreads();
        int sr[16], dr[16];
#pragma unroll
        for (int u = 0; u < 16; ++u) {
            const int e = base + u * 256 + t;    // coalesced
            if (e < E_TOT) {
                int s, d;
                if (e < N_EDGES) { s = ei[e]; d = ei[N_EDGES + e]; }
                else             { s = d = e - N_EDGES; }
                sr[u] = s; dr[u] = d;
                atomicAdd(&lcnt[d >> 10], 1);    // LDS
            } else dr[u] = -1;
        }
        __syncthreads();
        if (t < 128) {
            const int c = lcnt[t];
            lbase[t] = (c > 0) ? atomicAdd(&bcnt[t], c) : 0;   // global, 1/bucket
            lcnt[t] = 0;
        }
        __syncthreads();
#pragma unroll
        for (int u = 0; u < 16; ++u) {
            if (dr[u] >= 0) {
                const int bk = dr[u] >> 10;
                const int r = atomicAdd(&lcnt[bk], 1);         // LDS
                pairs[(size_t)bk * BSTRIDE + lbase[bk] + r] = (sr[u] << 10) | (dr[u] & 1023);
            }
        }
        return;
    }

    // ===== MFMA GEMM role =====
    const int lane = t & 63;
    const int w = t >> 6;                    // wave id == head id
    const int q = lane >> 4;                 // quad
    const int n15 = lane & 15;
    const int n0 = (int)blockIdx.x * 32;
    const int j0 = (2 * w) * 16 + n15;       // col in tile 0 of this head
    const int j1 = (2 * w + 1) * 16 + n15;   // col in tile 1

    f32x4 acc00 = {0.f, 0.f, 0.f, 0.f};
    f32x4 acc01 = acc00, acc10 = acc00, acc11 = acc00;

    for (int kt = 0; kt < 4; ++kt) {
        const int k0 = kt * 32 + q * 8;
        H8 A0, A1, B0, B1;
        {
            const float4* p = (const float4*)&x[(size_t)(n0 + n15) * 128 + k0];
            const float4 xa = p[0], xb = p[1];
            A0.h[0] = (_Float16)xa.x; A0.h[1] = (_Float16)xa.y;
            A0.h[2] = (_Float16)xa.z; A0.h[3] = (_Float16)xa.w;
            A0.h[4] = (_Float16)xb.x; A0.h[5] = (_Float16)xb.y;
            A0.h[6] = (_Float16)xb.z; A0.h[7] = (_Float16)xb.w;
        }
        {
            const float4* p = (const float4*)&x[(size_t)(n0 + 16 + n15) * 128 + k0];
            const float4 xa = p[0], xb = p[1];
            A1.h[0] = (_Float16)xa.x; A1.h[1] = (_Float16)xa.y;
            A1.h[2] = (_Float16)xa.z; A1.h[3] = (_Float16)xa.w;
            A1.h[4] = (_Float16)xb.x; A1.h[5] = (_Float16)xb.y;
            A1.h[6] = (_Float16)xb.z; A1.h[7] = (_Float16)xb.w;
        }
#pragma unroll
        for (int i = 0; i < 8; ++i) {
            B0.h[i] = (_Float16)W1[(size_t)(k0 + i) * 128 + j0];   // 16 lanes -> 64B runs, L2-hot
            B1.h[i] = (_Float16)W1[(size_t)(k0 + i) * 128 + j1];
        }
        acc00 = __builtin_amdgcn_mfma_f32_16x16x32_f16(A0.v, B0.v, acc00, 0, 0, 0);
        acc01 = __builtin_amdgcn_mfma_f32_16x16x32_f16(A0.v, B1.v, acc01, 0, 0, 0);
        acc10 = __builtin_amdgcn_mfma_f32_16x16x32_f16(A1.v, B0.v, acc10, 0, 0, 0);
        acc11 = __builtin_amdgcn_mfma_f32_16x16x32_f16(A1.v, B1.v, acc11, 0, 0, 0);
    }

    // Epilogue: D col = n15-based j, row m = q*4 + r. Fused attention dots.
    const float as0 = a_src1[j0], as1 = a_src1[j1];
    const float ad0 = a_dst1[j0], ad1 = a_dst1[j1];
#pragma unroll
    for (int ng = 0; ng < 2; ++ng) {
        const f32x4 accA = ng ? acc10 : acc00;
        const f32x4 accB = ng ? acc11 : acc01;
#pragma unroll
        for (int r = 0; r < 4; ++r) {
            const int node = n0 + ng * 16 + q * 4 + r;
            xw1h[(size_t)node * 128 + j0] = __float2half(accA[r]);   // 32B runs/quad
            xw1h[(size_t)node * 128 + j1] = __float2half(accB[r]);
            float ps = accA[r] * as0 + accB[r] * as1;
            float pd = accA[r] * ad0 + accB[r] * ad1;
#pragma unroll
            for (int o = 1; o < 16; o <<= 1) {   // reduce over the 16 j-lanes (quad preserved)
                ps += __shfl_xor(ps, o, 64);
                pd += __shfl_xor(pd, o, 64);
            }
            if (n15 == 0) {
                al1[(size_t)node * 4 + w] = ps;
                ar1[(size_t)node * 4 + w] = pd;
            }
        }
    }
}

// ---------------------------------------------------------------------------
// k_fill3: one 1024-thread block per bucket. Per-bucket counting sort with
// LDS histogram + LDS cursors — zero global atomics. Also emits ioff/deg.
// sbase: bcnt staged cooperatively into LDS (one coalesced read) then summed
// from LDS — replaces 127 serial dependent GLOBAL loads by thread 0.
// ---------------------------------------------------------------------------
__global__ __launch_bounds__(1024)
void k_fill3(const int* __restrict__ pairs, const int* __restrict__ bcnt,
             int* __restrict__ ioff, int* __restrict__ deg, int* __restrict__ ssrc) {
    const int bucket = blockIdx.x;
    const int t = threadIdx.x;
    const int cnt = bcnt[bucket];
    __shared__ int lhist[1024];
    __shared__ int lcur[1024];
    __shared__ int wsum[16];
    __shared__ int sbc[128];
    __shared__ int sbase;
    lhist[t] = 0;
    if (t < 128) sbc[t] = bcnt[t];           // coalesced, parallel
    __syncthreads();
    if (t == 0) {                            // sum lower buckets from LDS (pipelined)
        int b = 0;
        for (int k = 0; k < bucket; ++k) b += sbc[k];
        sbase = b;
    }
    for (int i = t; i < cnt; i += 1024) {
        const int p = pairs[(size_t)bucket * BSTRIDE + i];
        atomicAdd(&lhist[p & 1023], 1);
    }
    __syncthreads();
    const int v = lhist[t];
    int inc = v;
    const int lane = t & 63, wid = t >> 6;
#pragma unroll
    for (int o = 1; o < 64; o <<= 1) {
        const int nv = __shfl_up(inc, o, 64);
        if (lane >= o) inc += nv;
    }
    if (lane == 63) wsum[wid] = inc;
    __syncthreads();
    if (t == 0) {
        int acc = 0;
#pragma unroll
        for (int k = 0; k < 16; ++k) { const int tv = wsum[k]; wsum[k] = acc; acc += tv; }
    }
    __syncthreads();
    const int gofs = sbase + (inc - v) + wsum[wid];   // global CSR offset of node d
    const int d = bucket * 1024 + t;
    if (d < N_NODES) { ioff[d] = gofs; deg[d] = v; }
    lcur[t] = gofs;
    __syncthreads();
    for (int i = t; i < cnt; i += 1024) {
        const int p = pairs[(size_t)bucket * BSTRIDE + i];
        const int pos = atomicAdd(&lcur[p & 1023], 1);     // LDS
        ssrc[pos] = p >> 10;
    }
}

// ---------------------------------------------------------------------------
// Layer 1 pull-aggregation with FUSED layer-2 GEMM epilogue.
// One wave per dst node, zero barriers; uint4 gathers, 8 edges in flight.
// After the xor-16/32 reductions ALL 64 lanes hold the complete acc[8] and
// dnm, so the per-node 128x16 layer-2 GEMM decomposes in-wave: lane (g,c)
// owns h[8c..8c+7], computes partials for j=4g..4g+3 (W2 rows L1-hot, 8 KB),
// reduces over c via xor 1/2/4/8. Eliminates k_gemm2 and the entire
// out1h 25.6 MB write + 25.6 MB re-read round trip. h stays fp32 into the
// layer-2 GEMM (previously rounded to fp16 first) -> accuracy can only
// improve. All layer-2 state is loaded AFTER the main loop (R10).
// ---------------------------------------------------------------------------
__global__ __launch_bounds__(256)
void k_aggr1(const int* __restrict__ ssrc, const int* __restrict__ offs,
             const int* __restrict__ deg, const float* __restrict__ al1,
             const float* __restrict__ ar1, const __half* __restrict__ xw1h,
             const float* __restrict__ b1, const float* __restrict__ W2,
             const float* __restrict__ a_src2, const float* __restrict__ a_dst2,
             __half* __restrict__ xw2h, float* __restrict__ al2, float* __restrict__ ar2) {
    const int lane = threadIdx.x & 63;
    const int d = blockIdx.x * 4 + (threadIdx.x >> 6);
    const int g = lane >> 4;                 // edge group 0..3
    const int c = lane & 15;                 // col group: features 8c..8c+7
    const int h = c >> 2;                    // head of this col group
    const int beg = offs[d];
    const int n = deg[d];
    const float arh = ar1[(size_t)d * 4 + h];
    float acc[8] = {0.f, 0.f, 0.f, 0.f, 0.f, 0.f, 0.f, 0.f};
    float dnm = 0.f;

    for (int base = 0; base < n; base += 8) {
#pragma unroll
        for (int u = 0; u < 2; ++u) {
            const int e = base + u * 4 + g;
            const bool p = e < n;
            const int s = ssrc[beg + (p ? e : 0)];         // L1-hot (sequential)
            float v = al1[(size_t)s * 4 + h] + arh;        // broadcast gather
            v = v > 0.f ? v : NEG_SLOPE * v;
            const float w = p ? __expf(v) : 0.f;
            const uint4 rv = *(const uint4*)&xw1h[(size_t)s * 128 + c * 8];
            const float2 f0 = __half22float2(*(const __half2*)&rv.x);
            const float2 f1 = __half22float2(*(const __half2*)&rv.y);
            const float2 f2 = __half22float2(*(const __half2*)&rv.z);
            const float2 f3 = __half22float2(*(const __half2*)&rv.w);
            acc[0] = fmaf(w, f0.x, acc[0]); acc[1] = fmaf(w, f0.y, acc[1]);
            acc[2] = fmaf(w, f1.x, acc[2]); acc[3] = fmaf(w, f1.y, acc[3]);
            acc[4] = fmaf(w, f2.x, acc[4]); acc[5] = fmaf(w, f2.y, acc[5]);
            acc[6] = fmaf(w, f3.x, acc[6]); acc[7] = fmaf(w, f3.y, acc[7]);
            dnm += w;
        }
    }
#pragma unroll
    for (int i = 0; i < 8; ++i) {
        acc[i] += __shfl_xor(acc[i], 16, 64);
        acc[i] += __shfl_xor(acc[i], 32, 64);
    }
    dnm += __shfl_xor(dnm, 16, 64);
    dnm += __shfl_xor(dnm, 32, 64);

    // ===== fused layer-1 finish + layer-2 GEMM epilogue (all 64 lanes) =====
    const float rc = 1.f / dnm;
    const float4 b01 = *(const float4*)&b1[c * 8];
    const float4 b23 = *(const float4*)&b1[c * 8 + 4];
    const float bb[8] = {b01.x, b01.y, b01.z, b01.w, b23.x, b23.y, b23.z, b23.w};
    float hh[8];
#pragma unroll
    for (int i = 0; i < 8; ++i) {
        const float hv = acc[i] * rc + bb[i];
        hh[i] = hv > 0.f ? hv : 0.f;                       // bias + ReLU
    }
    // partials for outputs j = 4g .. 4g+3 over k = 8c .. 8c+7
    float pj0 = 0.f, pj1 = 0.f, pj2 = 0.f, pj3 = 0.f;
#pragma unroll
    for (int i = 0; i < 8; ++i) {
        const float4 wr = *(const float4*)&W2[(size_t)(c * 8 + i) * 16 + g * 4];  // L1-hot
        pj0 = fmaf(hh[i], wr.x, pj0);
        pj1 = fmaf(hh[i], wr.y, pj1);
        pj2 = fmaf(hh[i], wr.z, pj2);
        pj3 = fmaf(hh[i], wr.w, pj3);
    }
#pragma unroll
    for (int o = 1; o < 16; o <<= 1) {       // reduce over the 16 c-lanes (g preserved)
        pj0 += __shfl_xor(pj0, o, 64);
        pj1 += __shfl_xor(pj1, o, 64);
        pj2 += __shfl_xor(pj2, o, 64);
        pj3 += __shfl_xor(pj3, o, 64);
    }
    if (c == 0) {
        __half hj[4] = {__float2half(pj0), __float2half(pj1),
                        __float2half(pj2), __float2half(pj3)};
        *(uint2*)&xw2h[(size_t)d * 16 + g * 4] = *(const uint2*)hj;   // 8B store
    }
    const float4 as2 = *(const float4*)&a_src2[g * 4];
    const float4 ad2 = *(const float4*)&a_dst2[g * 4];
    float ps2 = pj0 * as2.x + pj1 * as2.y + pj2 * as2.z + pj3 * as2.w;
    float pd2 = pj0 * ad2.x + pj1 * ad2.y + pj2 * ad2.z + pj3 * ad2.w;
    ps2 += __shfl_xor(ps2, 16, 64); ps2 += __shfl_xor(ps2, 32, 64);
    pd2 += __shfl_xor(pd2, 16, 64); pd2 += __shfl_xor(pd2, 32, 64);
    if (lane == 0) { al2[d] = ps2; ar2[d] = pd2; }
}

// ---------------------------------------------------------------------------
// Layer 2 pull-aggregation: one wave per node; 16 edges in flight.
// ---------------------------------------------------------------------------
__global__ __launch_bounds__(256)
void k_aggr2(const int* __restrict__ ssrc, const int* __restrict__ offs,
             const int* __restrict__ deg, const float* __restrict__ al2,
             const float* __restrict__ ar2, const __half* __restrict__ xw2h,
             const float* __restrict__ b2, float* __restrict__ out) {
    const int lane = threadIdx.x & 63;
    const int node = blockIdx.x * 4 + (threadIdx.x >> 6);
    const int j2 = lane & 7;                 // feature pair 2*j2, 2*j2+1
    const int eL = lane >> 3;                // 0..7
    const int beg = offs[node];
    const int n = deg[node];
    const float ard = ar2[node];
    float a0 = 0.f, a1 = 0.f, dnm = 0.f;
    for (int base = 0; base < n; base += 16) {
#pragma unroll
        for (int u = 0; u < 2; ++u) {
            const int e = base + u * 8 + eL;
            const bool p = e < n;
            const int s = ssrc[beg + (p ? e : 0)];
            float v = al2[s] + ard;
            v = v > 0.f ? v : NEG_SLOPE * v;
            const float w = p ? __expf(v) : 0.f;
            const float2 f = __half22float2(*(const __half2*)&xw2h[(size_t)s * 16 + j2 * 2]);
            a0 = fmaf(w, f.x, a0);
            a1 = fmaf(w, f.y, a1);
            dnm += w;
        }
    }
#pragma unroll
    for (int o = 8; o < 64; o <<= 1) {
        a0 += __shfl_xor(a0, o, 64);
        a1 += __shfl_xor(a1, o, 64);
        dnm += __shfl_xor(dnm, o, 64);
    }
    if (eL == 0) {
        out[(size_t)node * 16 + j2 * 2]     = a0 / dnm + b2[j2 * 2];
        out[(size_t)node * 16 + j2 * 2 + 1] = a1 / dnm + b2[j2 * 2 + 1];
    }
}

extern "C" void kernel_launch(void* const* d_in, const int* in_sizes, int n_in,
                              void* d_out, int out_size, void* d_ws, size_t ws_size,
                              hipStream_t stream) {
    const float* x      = (const float*)d_in[0];
    const int*   ei     = (const int*)d_in[1];
    const float* W1     = (const float*)d_in[2];
    const float* a_src1 = (const float*)d_in[3];
    const float* a_dst1 = (const float*)d_in[4];
    const float* b1     = (const float*)d_in[5];
    const float* W2     = (const float*)d_in[6];
    const float* a_src2 = (const float*)d_in[7];
    const float* a_dst2 = (const float*)d_in[8];
    const float* b2     = (const float*)d_in[9];
    float* out = (float*)d_out;

    // Workspace (byte-addressed). Aliases:
    //  - region2 (formerly out1h) holds pairs (9.4 MB) for the partition/sort
    //    phase; once k_fill3 has consumed pairs, the SAME region holds
    //    xw2h/al2/ar2 written by the fused k_aggr1 epilogue. out1h no longer
    //    exists (k_gemm2 was fused into k_aggr1).
    char* wsb = (char*)d_ws;
    __half* xw1h = (__half*)wsb;                                  // N*128 half (25.6 MB)
    char* region2 = wsb + (size_t)N_NODES * 128 * 2;              // 25.6 MB region
    int*    pairs = (int*)region2;                                // 128*BSTRIDE int (9.4 MB)
    __half* xw2h  = (__half*)region2;                             // N*16 half (alias, after fill3)
    float*  al2   = (float*)(region2 + (size_t)N_NODES * 16 * 2); // N fp32
    float*  ar2   = al2 + N_NODES;                                // N fp32
    float*  al1  = (float*)(wsb + (size_t)N_NODES * 128 * 4);     // N*4 fp32
    float*  ar1  = al1 + (size_t)N_NODES * 4;                     // N*4
    int* ibcnt = (int*)(ar1 + (size_t)N_NODES * 4);               // 128 (zeroed)
    int* ioff  = ibcnt + 128;                                     // N
    int* ideg  = ioff + N_NODES;                                  // N
    int* isrc  = ideg + N_NODES;                                  // E_TOT

    hipMemsetAsync(ibcnt, 0, 128 * sizeof(int), stream);

    // Merged: MFMA layer-1 GEMM + edge bucket partition (independent roles).
    k_gemm1_part<<<NGEMM + NPART, 256, 0, stream>>>(x, W1, a_src1, a_dst1,
                                                    ei, ibcnt, pairs, xw1h, al1, ar1);
    // Per-bucket counting sort -> CSR (ioff/ideg/isrc).
    k_fill3<<<128, 1024, 0, stream>>>(pairs, ibcnt, ioff, ideg, isrc);

    // Layer 1 aggregation + fused layer-2 GEMM (k_gemm2 eliminated).
    k_aggr1<<<N_NODES / 4, 256, 0, stream>>>(isrc, ioff, ideg, al1, ar1, xw1h, b1,
                                             W2, a_src2, a_dst2, xw2h, al2, ar2);

    // Layer 2 aggregation
    k_aggr2<<<N_NODES / 4, 256, 0, stream>>>(isrc, ioff, ideg, al2, ar2, xw2h, b2, out);
}

// Round 2
// 310.841 us; speedup vs baseline: 1.1689x; 1.1689x over previous
//
#include <hip/hip_runtime.h>
#include <hip/hip_fp16.h>

#define N_NODES 100000
#define N_EDGES 1600000
#define E_TOT   (N_EDGES + N_NODES)   // 1,700,000 incl. self-loops
#define NEG_SLOPE 0.2f
#define PART_EPB 4096                 // edges per partition block
#define BSTRIDE 18432                 // slots per bucket region (mean 17408 + 7.8 sigma)
#define NGEMM (N_NODES / 32)          // 3125 gemm blocks
#define NPART ((E_TOT + PART_EPB - 1) / PART_EPB)   // 416 partition blocks

using f16x8 = __attribute__((ext_vector_type(8))) _Float16;
using f32x4 = __attribute__((ext_vector_type(4))) float;
union H8 { f16x8 v; _Float16 h[8]; };

// ---------------------------------------------------------------------------
// Merged kernel: blocks < NGEMM do the layer-1 GEMM via MFMA (fp16 in, fp32
// acc). Blocks >= NGEMM do the edge bucket-partition (zero data dependency
// between the roles -> one dispatch, overlapped).
// ---------------------------------------------------------------------------
__global__ __launch_bounds__(256)
void k_gemm1_part(const float* __restrict__ x, const float* __restrict__ W1,
                  const float* __restrict__ a_src1, const float* __restrict__ a_dst1,
                  const int* __restrict__ ei, int* __restrict__ bcnt, int* __restrict__ pairs,
                  __half* __restrict__ xw1h, float* __restrict__ al1, float* __restrict__ ar1) {
    __shared__ int lcnt[128];
    __shared__ int lbase[128];
    const int t = threadIdx.x;

    if (blockIdx.x >= NGEMM) {
        // ===== edge-partition role =====
        const int base = ((int)blockIdx.x - NGEMM) * PART_EPB;
        if (t < 128) lcnt[t] = 0;
        __syncthreads();
        int sr[16], dr[16];
#pragma unroll
        for (int u = 0; u < 16; ++u) {
            const int e = base + u * 256 + t;    // coalesced
            if (e < E_TOT) {
                int s, d;
                if (e < N_EDGES) { s = ei[e]; d = ei[N_EDGES + e]; }
                else             { s = d = e - N_EDGES; }
                sr[u] = s; dr[u] = d;
                atomicAdd(&lcnt[d >> 10], 1);    // LDS
            } else dr[u] = -1;
        }
        __syncthreads();
        if (t < 128) {
            const int c = lcnt[t];
            lbase[t] = (c > 0) ? atomicAdd(&bcnt[t], c) : 0;   // global, 1/bucket
            lcnt[t] = 0;
        }
        __syncthreads();
#pragma unroll
        for (int u = 0; u < 16; ++u) {
            if (dr[u] >= 0) {
                const int bk = dr[u] >> 10;
                const int r = atomicAdd(&lcnt[bk], 1);         // LDS
                pairs[(size_t)bk * BSTRIDE + lbase[bk] + r] = (sr[u] << 10) | (dr[u] & 1023);
            }
        }
        return;
    }

    // ===== MFMA GEMM role =====
    const int lane = t & 63;
    const int w = t >> 6;                    // wave id == head id
    const int q = lane >> 4;                 // quad
    const int n15 = lane & 15;
    const int n0 = (int)blockIdx.x * 32;
    const int j0 = (2 * w) * 16 + n15;       // col in tile 0 of this head
    const int j1 = (2 * w + 1) * 16 + n15;   // col in tile 1

    f32x4 acc00 = {0.f, 0.f, 0.f, 0.f};
    f32x4 acc01 = acc00, acc10 = acc00, acc11 = acc00;

    for (int kt = 0; kt < 4; ++kt) {
        const int k0 = kt * 32 + q * 8;
        H8 A0, A1, B0, B1;
        {
            const float4* p = (const float4*)&x[(size_t)(n0 + n15) * 128 + k0];
            const float4 xa = p[0], xb = p[1];
            A0.h[0] = (_Float16)xa.x; A0.h[1] = (_Float16)xa.y;
            A0.h[2] = (_Float16)xa.z; A0.h[3] = (_Float16)xa.w;
            A0.h[4] = (_Float16)xb.x; A0.h[5] = (_Float16)xb.y;
            A0.h[6] = (_Float16)xb.z; A0.h[7] = (_Float16)xb.w;
        }
        {
            const float4* p = (const float4*)&x[(size_t)(n0 + 16 + n15) * 128 + k0];
            const float4 xa = p[0], xb = p[1];
            A1.h[0] = (_Float16)xa.x; A1.h[1] = (_Float16)xa.y;
            A1.h[2] = (_Float16)xa.z; A1.h[3] = (_Float16)xa.w;
            A1.h[4] = (_Float16)xb.x; A1.h[5] = (_Float16)xb.y;
            A1.h[6] = (_Float16)xb.z; A1.h[7] = (_Float16)xb.w;
        }
#pragma unroll
        for (int i = 0; i < 8; ++i) {
            B0.h[i] = (_Float16)W1[(size_t)(k0 + i) * 128 + j0];   // 16 lanes -> 64B runs, L2-hot
            B1.h[i] = (_Float16)W1[(size_t)(k0 + i) * 128 + j1];
        }
        acc00 = __builtin_amdgcn_mfma_f32_16x16x32_f16(A0.v, B0.v, acc00, 0, 0, 0);
        acc01 = __builtin_amdgcn_mfma_f32_16x16x32_f16(A0.v, B1.v, acc01, 0, 0, 0);
        acc10 = __builtin_amdgcn_mfma_f32_16x16x32_f16(A1.v, B0.v, acc10, 0, 0, 0);
        acc11 = __builtin_amdgcn_mfma_f32_16x16x32_f16(A1.v, B1.v, acc11, 0, 0, 0);
    }

    // Epilogue: D col = n15-based j, row m = q*4 + r. Fused attention dots.
    const float as0 = a_src1[j0], as1 = a_src1[j1];
    const float ad0 = a_dst1[j0], ad1 = a_dst1[j1];
#pragma unroll
    for (int ng = 0; ng < 2; ++ng) {
        const f32x4 accA = ng ? acc10 : acc00;
        const f32x4 accB = ng ? acc11 : acc01;
#pragma unroll
        for (int r = 0; r < 4; ++r) {
            const int node = n0 + ng * 16 + q * 4 + r;
            xw1h[(size_t)node * 128 + j0] = __float2half(accA[r]);   // 32B runs/quad
            xw1h[(size_t)node * 128 + j1] = __float2half(accB[r]);
            float ps = accA[r] * as0 + accB[r] * as1;
            float pd = accA[r] * ad0 + accB[r] * ad1;
#pragma unroll
            for (int o = 1; o < 16; o <<= 1) {   // reduce over the 16 j-lanes (quad preserved)
                ps += __shfl_xor(ps, o, 64);
                pd += __shfl_xor(pd, o, 64);
            }
            if (n15 == 0) {
                al1[(size_t)node * 4 + w] = ps;
                ar1[(size_t)node * 4 + w] = pd;
            }
        }
    }
}

// ---------------------------------------------------------------------------
// k_fill3: one 1024-thread block per bucket. Per-bucket counting sort with
// LDS histogram + LDS cursors — zero global atomics. Also emits ioff/deg.
// sbase: bcnt staged cooperatively into LDS (one coalesced read) then summed
// from LDS — replaces 127 serial dependent GLOBAL loads by thread 0.
// ---------------------------------------------------------------------------
__global__ __launch_bounds__(1024)
void k_fill3(const int* __restrict__ pairs, const int* __restrict__ bcnt,
             int* __restrict__ ioff, int* __restrict__ deg, int* __restrict__ ssrc) {
    const int bucket = blockIdx.x;
    const int t = threadIdx.x;
    const int cnt = bcnt[bucket];
    __shared__ int lhist[1024];
    __shared__ int lcur[1024];
    __shared__ int wsum[16];
    __shared__ int sbc[128];
    __shared__ int sbase;
    lhist[t] = 0;
    if (t < 128) sbc[t] = bcnt[t];           // coalesced, parallel
    __syncthreads();
    if (t == 0) {                            // sum lower buckets from LDS (pipelined)
        int b = 0;
        for (int k = 0; k < bucket; ++k) b += sbc[k];
        sbase = b;
    }
    for (int i = t; i < cnt; i += 1024) {
        const int p = pairs[(size_t)bucket * BSTRIDE + i];
        atomicAdd(&lhist[p & 1023], 1);
    }
    __syncthreads();
    const int v = lhist[t];
    int inc = v;
    const int lane = t & 63, wid = t >> 6;
#pragma unroll
    for (int o = 1; o < 64; o <<= 1) {
        const int nv = __shfl_up(inc, o, 64);
        if (lane >= o) inc += nv;
    }
    if (lane == 63) wsum[wid] = inc;
    __syncthreads();
    if (t == 0) {
        int acc = 0;
#pragma unroll
        for (int k = 0; k < 16; ++k) { const int tv = wsum[k]; wsum[k] = acc; acc += tv; }
    }
    __syncthreads();
    const int gofs = sbase + (inc - v) + wsum[wid];   // global CSR offset of node d
    const int d = bucket * 1024 + t;
    if (d < N_NODES) { ioff[d] = gofs; deg[d] = v; }
    lcur[t] = gofs;
    __syncthreads();
    for (int i = t; i < cnt; i += 1024) {
        const int p = pairs[(size_t)bucket * BSTRIDE + i];
        const int pos = atomicAdd(&lcur[p & 1023], 1);     // LDS
        ssrc[pos] = p >> 10;
    }
}

// ---------------------------------------------------------------------------
// Layer 1 pull-aggregation (VGPR 20 — do NOT preload epilogue state, R10;
// do NOT fuse the layer-2 GEMM here, R1 of this session: the epilogue lands
// on the wave critical path of a ~2-iteration gather loop and halves the
// sustained gather BW, +67us).
// One wave per dst node, zero barriers; uint4 gathers, 8 edges in flight.
// ---------------------------------------------------------------------------
__global__ __launch_bounds__(256)
void k_aggr1(const int* __restrict__ ssrc, const int* __restrict__ offs,
             const int* __restrict__ deg, const float* __restrict__ al1,
             const float* __restrict__ ar1, const __half* __restrict__ xw1h,
             const float* __restrict__ b1, __half* __restrict__ out1h) {
    const int lane = threadIdx.x & 63;
    const int d = blockIdx.x * 4 + (threadIdx.x >> 6);
    const int g = lane >> 4;                 // edge group 0..3
    const int c = lane & 15;                 // col group: features 8c..8c+7
    const int h = c >> 2;                    // head of this col group
    const int beg = offs[d];
    const int n = deg[d];
    const float arh = ar1[(size_t)d * 4 + h];
    float acc[8] = {0.f, 0.f, 0.f, 0.f, 0.f, 0.f, 0.f, 0.f};
    float dnm = 0.f;

    for (int base = 0; base < n; base += 8) {
#pragma unroll
        for (int u = 0; u < 2; ++u) {
            const int e = base + u * 4 + g;
            const bool p = e < n;
            const int s = ssrc[beg + (p ? e : 0)];         // L1-hot (sequential)
            float v = al1[(size_t)s * 4 + h] + arh;        // broadcast gather
            v = v > 0.f ? v : NEG_SLOPE * v;
            const float w = p ? __expf(v) : 0.f;
            const uint4 rv = *(const uint4*)&xw1h[(size_t)s * 128 + c * 8];
            const float2 f0 = __half22float2(*(const __half2*)&rv.x);
            const float2 f1 = __half22float2(*(const __half2*)&rv.y);
            const float2 f2 = __half22float2(*(const __half2*)&rv.z);
            const float2 f3 = __half22float2(*(const __half2*)&rv.w);
            acc[0] = fmaf(w, f0.x, acc[0]); acc[1] = fmaf(w, f0.y, acc[1]);
            acc[2] = fmaf(w, f1.x, acc[2]); acc[3] = fmaf(w, f1.y, acc[3]);
            acc[4] = fmaf(w, f2.x, acc[4]); acc[5] = fmaf(w, f2.y, acc[5]);
            acc[6] = fmaf(w, f3.x, acc[6]); acc[7] = fmaf(w, f3.y, acc[7]);
            dnm += w;
        }
    }
#pragma unroll
    for (int i = 0; i < 8; ++i) {
        acc[i] += __shfl_xor(acc[i], 16, 64);
        acc[i] += __shfl_xor(acc[i], 32, 64);
    }
    dnm += __shfl_xor(dnm, 16, 64);
    dnm += __shfl_xor(dnm, 32, 64);
    if (g == 0) {
        const float rc = 1.f / dnm;
        const float4 b01 = *(const float4*)&b1[c * 8];
        const float4 b23 = *(const float4*)&b1[c * 8 + 4];
        const float bb[8] = {b01.x, b01.y, b01.z, b01.w, b23.x, b23.y, b23.z, b23.w};
        __half ho[8];
#pragma unroll
        for (int i = 0; i < 8; ++i) {
            const float hv = acc[i] * rc + bb[i];
            ho[i] = __float2half(hv > 0.f ? hv : 0.f);     // bias + ReLU
        }
        *(uint4*)&out1h[(size_t)d * 128 + c * 8] = *(uint4*)ho;
    }
}

// ---------------------------------------------------------------------------
// Layer 2 GEMM via MFMA (replaces the scalar LDS version: that one issued
// 256 ds_read_b32 per wave -> LDS-issue-bound, ~40us for a 29MB op).
// 64 nodes/block, 4 waves; wave w owns the 16-node M-tile starting at
// blockIdx*64 + w*16. N=16 output cols = one tile; K=128 = 4 k-steps ->
// 4 MFMAs/wave. A-frags are direct 16B loads of out1h (already fp16, layout
// A[m=lane&15][k=quad*8+i] matches the row-major 16B run). B-frags scalar-
// load W2 (8KB, L2-hot). Epilogue fuses the a_src2/a_dst2 dots.
// ---------------------------------------------------------------------------
__global__ __launch_bounds__(256)
void k_gemm2m(const __half* __restrict__ out1h, const float* __restrict__ W2,
              const float* __restrict__ a_src2, const float* __restrict__ a_dst2,
              __half* __restrict__ xw2h, float* __restrict__ al2, float* __restrict__ ar2) {
    const int t = threadIdx.x;
    const int lane = t & 63;
    const int w = t >> 6;
    const int q = lane >> 4;
    const int n15 = lane & 15;
    const int n0 = (int)blockIdx.x * 64 + w * 16;
    const int ra = n0 + n15;
    const size_t rowA = (ra < N_NODES) ? (size_t)ra : (size_t)(N_NODES - 1);  // clamp tail

    f32x4 acc = {0.f, 0.f, 0.f, 0.f};
#pragma unroll
    for (int kt = 0; kt < 4; ++kt) {
        const int k0 = kt * 32 + q * 8;
        H8 A, B;
        A.v = *(const f16x8*)&out1h[rowA * 128 + k0];          // 16B, coalesced 32B runs/quad
#pragma unroll
        for (int i = 0; i < 8; ++i)
            B.h[i] = (_Float16)W2[(size_t)(k0 + i) * 16 + n15]; // 64B runs, L2-hot
        acc = __builtin_amdgcn_mfma_f32_16x16x32_f16(A.v, B.v, acc, 0, 0, 0);
    }

    // C/D: col j = n15, row m = q*4 + r. Fused attention dots (reduce over j).
    const float as = a_src2[n15], ad = a_dst2[n15];
#pragma unroll
    for (int r = 0; r < 4; ++r) {
        const int node = n0 + q * 4 + r;
        float ps = acc[r] * as;
        float pd = acc[r] * ad;
#pragma unroll
        for (int o = 1; o < 16; o <<= 1) {
            ps += __shfl_xor(ps, o, 64);
            pd += __shfl_xor(pd, o, 64);
        }
        if (node < N_NODES) {
            xw2h[(size_t)node * 16 + n15] = __float2half(acc[r]);  // 32B runs/quad
            if (n15 == 0) { al2[node] = ps; ar2[node] = pd; }
        }
    }
}

// ---------------------------------------------------------------------------
// Layer 2 pull-aggregation: one wave per node; 16 edges in flight.
// ---------------------------------------------------------------------------
__global__ __launch_bounds__(256)
void k_aggr2(const int* __restrict__ ssrc, const int* __restrict__ offs,
             const int* __restrict__ deg, const float* __restrict__ al2,
             const float* __restrict__ ar2, const __half* __restrict__ xw2h,
             const float* __restrict__ b2, float* __restrict__ out) {
    const int lane = threadIdx.x & 63;
    const int node = blockIdx.x * 4 + (threadIdx.x >> 6);
    const int j2 = lane & 7;                 // feature pair 2*j2, 2*j2+1
    const int eL = lane >> 3;                // 0..7
    const int beg = offs[node];
    const int n = deg[node];
    const float ard = ar2[node];
    float a0 = 0.f, a1 = 0.f, dnm = 0.f;
    for (int base = 0; base < n; base += 16) {
#pragma unroll
        for (int u = 0; u < 2; ++u) {
            const int e = base + u * 8 + eL;
            const bool p = e < n;
            const int s = ssrc[beg + (p ? e : 0)];
            float v = al2[s] + ard;
            v = v > 0.f ? v : NEG_SLOPE * v;
            const float w = p ? __expf(v) : 0.f;
            const float2 f = __half22float2(*(const __half2*)&xw2h[(size_t)s * 16 + j2 * 2]);
            a0 = fmaf(w, f.x, a0);
            a1 = fmaf(w, f.y, a1);
            dnm += w;
        }
    }
#pragma unroll
    for (int o = 8; o < 64; o <<= 1) {
        a0 += __shfl_xor(a0, o, 64);
        a1 += __shfl_xor(a1, o, 64);
        dnm += __shfl_xor(dnm, o, 64);
    }
    if (eL == 0) {
        out[(size_t)node * 16 + j2 * 2]     = a0 / dnm + b2[j2 * 2];
        out[(size_t)node * 16 + j2 * 2 + 1] = a1 / dnm + b2[j2 * 2 + 1];
    }
}

extern "C" void kernel_launch(void* const* d_in, const int* in_sizes, int n_in,
                              void* d_out, int out_size, void* d_ws, size_t ws_size,
                              hipStream_t stream) {
    const float* x      = (const float*)d_in[0];
    const int*   ei     = (const int*)d_in[1];
    const float* W1     = (const float*)d_in[2];
    const float* a_src1 = (const float*)d_in[3];
    const float* a_dst1 = (const float*)d_in[4];
    const float* b1     = (const float*)d_in[5];
    const float* W2     = (const float*)d_in[6];
    const float* a_src2 = (const float*)d_in[7];
    const float* a_dst2 = (const float*)d_in[8];
    const float* b2     = (const float*)d_in[9];
    float* out = (float*)d_out;

    // Workspace (byte-addressed). Aliases:
    //  - pairs (9.4MB packed) sits in out1h's region: consumed by k_fill3
    //    before k_aggr1 writes out1h.
    //  - xw2h/al2/ar2 sit in xw1h's region: written by k_gemm2m after k_aggr1
    //    is done with xw1h.
    char* wsb = (char*)d_ws;
    __half* xw1h = (__half*)wsb;                                  // N*128 half (25.6 MB)
    __half* xw2h = (__half*)wsb;                                  // N*16 half (alias)
    float*  al2  = (float*)(wsb + (size_t)N_NODES * 16 * 2);      // N fp32 (alias)
    float*  ar2  = al2 + N_NODES;                                 // N fp32 (alias)
    __half* out1h = (__half*)(wsb + (size_t)N_NODES * 128 * 2);   // N*128 half (25.6 MB)
    int*    pairs = (int*)out1h;                                  // 128*BSTRIDE int (alias, 9.4 MB)
    float*  al1  = (float*)(wsb + (size_t)N_NODES * 128 * 4);     // N*4 fp32
    float*  ar1  = al1 + (size_t)N_NODES * 4;                     // N*4
    int* ibcnt = (int*)(ar1 + (size_t)N_NODES * 4);               // 128 (zeroed)
    int* ioff  = ibcnt + 128;                                     // N
    int* ideg  = ioff + N_NODES;                                  // N
    int* isrc  = ideg + N_NODES;                                  // E_TOT

    hipMemsetAsync(ibcnt, 0, 128 * sizeof(int), stream);

    // Merged: MFMA layer-1 GEMM + edge bucket partition (independent roles).
    k_gemm1_part<<<NGEMM + NPART, 256, 0, stream>>>(x, W1, a_src1, a_dst1,
                                                    ei, ibcnt, pairs, xw1h, al1, ar1);
    // Per-bucket counting sort -> CSR (ioff/ideg/isrc).
    k_fill3<<<128, 1024, 0, stream>>>(pairs, ibcnt, ioff, ideg, isrc);

    // Layer 1 aggregation
    k_aggr1<<<N_NODES / 4, 256, 0, stream>>>(isrc, ioff, ideg, al1, ar1, xw1h, b1, out1h);

    // Layer 2 GEMM (MFMA) + fused attention dots
    k_gemm2m<<<(N_NODES + 63) / 64, 256, 0, stream>>>(out1h, W2, a_src2, a_dst2, xw2h, al2, ar2);

    // Layer 2 aggregation
    k_aggr2<<<N_NODES / 4, 256, 0, stream>>>(isrc, ioff, ideg, al2, ar2, xw2h, b2, out);
}

// Round 3
// 309.890 us; speedup vs baseline: 1.1724x; 1.0031x over previous
//
#include <hip/hip_runtime.h>
#include <hip/hip_fp16.h>

#define N_NODES 100000
#define N_EDGES 1600000
#define E_TOT   (N_EDGES + N_NODES)   // 1,700,000 incl. self-loops
#define NEG_SLOPE 0.2f
#define PART_EPB 4096                 // edges per partition block
#define BSTRIDE 18432                 // slots per bucket region (mean 17408 + 7.8 sigma)
#define NGEMM (N_NODES / 32)          // 3125 gemm blocks
#define NPART ((E_TOT + PART_EPB - 1) / PART_EPB)   // 416 partition blocks

using f16x8 = __attribute__((ext_vector_type(8))) _Float16;
using f32x4 = __attribute__((ext_vector_type(4))) float;
union H8 { f16x8 v; _Float16 h[8]; __half2 h2[4]; };

// ---------------------------------------------------------------------------
// Merged kernel: blocks < NGEMM do the layer-1 GEMM via MFMA (fp16 in, fp32
// acc). Blocks >= NGEMM do the edge bucket-partition (zero data dependency
// between the roles -> one dispatch, overlapped).
// f32->f16 uses packed v_cvt_pkrtz (via __float22half2_rn): halves the
// cvt-path VALU ops vs scalar casts.
// ---------------------------------------------------------------------------
__global__ __launch_bounds__(256)
void k_gemm1_part(const float* __restrict__ x, const float* __restrict__ W1,
                  const float* __restrict__ a_src1, const float* __restrict__ a_dst1,
                  const int* __restrict__ ei, int* __restrict__ bcnt, int* __restrict__ pairs,
                  __half* __restrict__ xw1h, float* __restrict__ al1, float* __restrict__ ar1) {
    __shared__ int lcnt[128];
    __shared__ int lbase[128];
    const int t = threadIdx.x;

    if (blockIdx.x >= NGEMM) {
        // ===== edge-partition role =====
        const int base = ((int)blockIdx.x - NGEMM) * PART_EPB;
        if (t < 128) lcnt[t] = 0;
        __syncthreads();
        int sr[16], dr[16];
#pragma unroll
        for (int u = 0; u < 16; ++u) {
            const int e = base + u * 256 + t;    // coalesced
            if (e < E_TOT) {
                int s, d;
                if (e < N_EDGES) { s = ei[e]; d = ei[N_EDGES + e]; }
                else             { s = d = e - N_EDGES; }
                sr[u] = s; dr[u] = d;
                atomicAdd(&lcnt[d >> 10], 1);    // LDS
            } else dr[u] = -1;
        }
        __syncthreads();
        if (t < 128) {
            const int c = lcnt[t];
            lbase[t] = (c > 0) ? atomicAdd(&bcnt[t], c) : 0;   // global, 1/bucket
            lcnt[t] = 0;
        }
        __syncthreads();
#pragma unroll
        for (int u = 0; u < 16; ++u) {
            if (dr[u] >= 0) {
                const int bk = dr[u] >> 10;
                const int r = atomicAdd(&lcnt[bk], 1);         // LDS
                pairs[(size_t)bk * BSTRIDE + lbase[bk] + r] = (sr[u] << 10) | (dr[u] & 1023);
            }
        }
        return;
    }

    // ===== MFMA GEMM role =====
    const int lane = t & 63;
    const int w = t >> 6;                    // wave id == head id
    const int q = lane >> 4;                 // quad
    const int n15 = lane & 15;
    const int n0 = (int)blockIdx.x * 32;
    const int j0 = (2 * w) * 16 + n15;       // col in tile 0 of this head
    const int j1 = (2 * w + 1) * 16 + n15;   // col in tile 1

    f32x4 acc00 = {0.f, 0.f, 0.f, 0.f};
    f32x4 acc01 = acc00, acc10 = acc00, acc11 = acc00;

    for (int kt = 0; kt < 4; ++kt) {
        const int k0 = kt * 32 + q * 8;
        H8 A0, A1, B0, B1;
        {
            const float4* p = (const float4*)&x[(size_t)(n0 + n15) * 128 + k0];
            const float4 xa = p[0], xb = p[1];
            A0.h2[0] = __float22half2_rn(make_float2(xa.x, xa.y));
            A0.h2[1] = __float22half2_rn(make_float2(xa.z, xa.w));
            A0.h2[2] = __float22half2_rn(make_float2(xb.x, xb.y));
            A0.h2[3] = __float22half2_rn(make_float2(xb.z, xb.w));
        }
        {
            const float4* p = (const float4*)&x[(size_t)(n0 + 16 + n15) * 128 + k0];
            const float4 xa = p[0], xb = p[1];
            A1.h2[0] = __float22half2_rn(make_float2(xa.x, xa.y));
            A1.h2[1] = __float22half2_rn(make_float2(xa.z, xa.w));
            A1.h2[2] = __float22half2_rn(make_float2(xb.x, xb.y));
            A1.h2[3] = __float22half2_rn(make_float2(xb.z, xb.w));
        }
        {
            float w0[8], w1[8];
#pragma unroll
            for (int i = 0; i < 8; ++i) {
                w0[i] = W1[(size_t)(k0 + i) * 128 + j0];   // 64B runs, L2-hot
                w1[i] = W1[(size_t)(k0 + i) * 128 + j1];
            }
#pragma unroll
            for (int i = 0; i < 4; ++i) {
                B0.h2[i] = __float22half2_rn(make_float2(w0[2 * i], w0[2 * i + 1]));
                B1.h2[i] = __float22half2_rn(make_float2(w1[2 * i], w1[2 * i + 1]));
            }
        }
        acc00 = __builtin_amdgcn_mfma_f32_16x16x32_f16(A0.v, B0.v, acc00, 0, 0, 0);
        acc01 = __builtin_amdgcn_mfma_f32_16x16x32_f16(A0.v, B1.v, acc01, 0, 0, 0);
        acc10 = __builtin_amdgcn_mfma_f32_16x16x32_f16(A1.v, B0.v, acc10, 0, 0, 0);
        acc11 = __builtin_amdgcn_mfma_f32_16x16x32_f16(A1.v, B1.v, acc11, 0, 0, 0);
    }

    // Epilogue: D col = n15-based j, row m = q*4 + r. Fused attention dots.
    const float as0 = a_src1[j0], as1 = a_src1[j1];
    const float ad0 = a_dst1[j0], ad1 = a_dst1[j1];
#pragma unroll
    for (int ng = 0; ng < 2; ++ng) {
        const f32x4 accA = ng ? acc10 : acc00;
        const f32x4 accB = ng ? acc11 : acc01;
#pragma unroll
        for (int r = 0; r < 4; ++r) {
            const int node = n0 + ng * 16 + q * 4 + r;
            xw1h[(size_t)node * 128 + j0] = __float2half(accA[r]);   // 32B runs/quad
            xw1h[(size_t)node * 128 + j1] = __float2half(accB[r]);
            float ps = accA[r] * as0 + accB[r] * as1;
            float pd = accA[r] * ad0 + accB[r] * ad1;
#pragma unroll
            for (int o = 1; o < 16; o <<= 1) {   // reduce over the 16 j-lanes (quad preserved)
                ps += __shfl_xor(ps, o, 64);
                pd += __shfl_xor(pd, o, 64);
            }
            if (n15 == 0) {
                al1[(size_t)node * 4 + w] = ps;
                ar1[(size_t)node * 4 + w] = pd;
            }
        }
    }
}

// ---------------------------------------------------------------------------
// k_fill3: one 1024-thread block per bucket. Per-bucket counting sort with
// LDS histogram + LDS cursors — zero global atomics. Also emits ioff/deg.
// sbase: bcnt staged cooperatively into LDS (one coalesced read) then summed
// from LDS.
// ---------------------------------------------------------------------------
__global__ __launch_bounds__(1024)
void k_fill3(const int* __restrict__ pairs, const int* __restrict__ bcnt,
             int* __restrict__ ioff, int* __restrict__ deg, int* __restrict__ ssrc) {
    const int bucket = blockIdx.x;
    const int t = threadIdx.x;
    const int cnt = bcnt[bucket];
    __shared__ int lhist[1024];
    __shared__ int lcur[1024];
    __shared__ int wsum[16];
    __shared__ int sbc[128];
    __shared__ int sbase;
    lhist[t] = 0;
    if (t < 128) sbc[t] = bcnt[t];           // coalesced, parallel
    __syncthreads();
    if (t == 0) {                            // sum lower buckets from LDS (pipelined)
        int b = 0;
        for (int k = 0; k < bucket; ++k) b += sbc[k];
        sbase = b;
    }
    for (int i = t; i < cnt; i += 1024) {
        const int p = pairs[(size_t)bucket * BSTRIDE + i];
        atomicAdd(&lhist[p & 1023], 1);
    }
    __syncthreads();
    const int v = lhist[t];
    int inc = v;
    const int lane = t & 63, wid = t >> 6;
#pragma unroll
    for (int o = 1; o < 64; o <<= 1) {
        const int nv = __shfl_up(inc, o, 64);
        if (lane >= o) inc += nv;
    }
    if (lane == 63) wsum[wid] = inc;
    __syncthreads();
    if (t == 0) {
        int acc = 0;
#pragma unroll
        for (int k = 0; k < 16; ++k) { const int tv = wsum[k]; wsum[k] = acc; acc += tv; }
    }
    __syncthreads();
    const int gofs = sbase + (inc - v) + wsum[wid];   // global CSR offset of node d
    const int d = bucket * 1024 + t;
    if (d < N_NODES) { ioff[d] = gofs; deg[d] = v; }
    lcur[t] = gofs;
    __syncthreads();
    for (int i = t; i < cnt; i += 1024) {
        const int p = pairs[(size_t)bucket * BSTRIDE + i];
        const int pos = atomicAdd(&lcur[p & 1023], 1);     // LDS
        ssrc[pos] = p >> 10;
    }
}

// ---------------------------------------------------------------------------
// Layer 1 pull-aggregation. One wave per dst node, zero barriers.
// R3: 16 edges in flight (was 8) — mean degree 17 means the wave previously
// paid ~2 dependent HBM rounds; doubling MLP halves the rounds. VGPR ~40,
// still far below any occupancy cliff (thread count caps at 8 waves/SIMD).
// Do NOT preload epilogue state (R10); do NOT fuse layer-2 GEMM here (R1).
// ---------------------------------------------------------------------------
__global__ __launch_bounds__(256)
void k_aggr1(const int* __restrict__ ssrc, const int* __restrict__ offs,
             const int* __restrict__ deg, const float* __restrict__ al1,
             const float* __restrict__ ar1, const __half* __restrict__ xw1h,
             const float* __restrict__ b1, __half* __restrict__ out1h) {
    const int lane = threadIdx.x & 63;
    const int d = blockIdx.x * 4 + (threadIdx.x >> 6);
    const int g = lane >> 4;                 // edge group 0..3
    const int c = lane & 15;                 // col group: features 8c..8c+7
    const int h = c >> 2;                    // head of this col group
    const int beg = offs[d];
    const int n = deg[d];
    const float arh = ar1[(size_t)d * 4 + h];
    float acc[8] = {0.f, 0.f, 0.f, 0.f, 0.f, 0.f, 0.f, 0.f};
    float dnm = 0.f;

    for (int base = 0; base < n; base += 16) {
#pragma unroll
        for (int u = 0; u < 4; ++u) {
            const int e = base + u * 4 + g;
            const bool p = e < n;
            const int s = ssrc[beg + (p ? e : 0)];         // L1-hot (sequential)
            float v = al1[(size_t)s * 4 + h] + arh;        // broadcast gather
            v = v > 0.f ? v : NEG_SLOPE * v;
            const float w = p ? __expf(v) : 0.f;
            const uint4 rv = *(const uint4*)&xw1h[(size_t)s * 128 + c * 8];
            const float2 f0 = __half22float2(*(const __half2*)&rv.x);
            const float2 f1 = __half22float2(*(const __half2*)&rv.y);
            const float2 f2 = __half22float2(*(const __half2*)&rv.z);
            const float2 f3 = __half22float2(*(const __half2*)&rv.w);
            acc[0] = fmaf(w, f0.x, acc[0]); acc[1] = fmaf(w, f0.y, acc[1]);
            acc[2] = fmaf(w, f1.x, acc[2]); acc[3] = fmaf(w, f1.y, acc[3]);
            acc[4] = fmaf(w, f2.x, acc[4]); acc[5] = fmaf(w, f2.y, acc[5]);
            acc[6] = fmaf(w, f3.x, acc[6]); acc[7] = fmaf(w, f3.y, acc[7]);
            dnm += w;
        }
    }
#pragma unroll
    for (int i = 0; i < 8; ++i) {
        acc[i] += __shfl_xor(acc[i], 16, 64);
        acc[i] += __shfl_xor(acc[i], 32, 64);
    }
    dnm += __shfl_xor(dnm, 16, 64);
    dnm += __shfl_xor(dnm, 32, 64);
    if (g == 0) {
        const float rc = 1.f / dnm;
        const float4 b01 = *(const float4*)&b1[c * 8];
        const float4 b23 = *(const float4*)&b1[c * 8 + 4];
        const float bb[8] = {b01.x, b01.y, b01.z, b01.w, b23.x, b23.y, b23.z, b23.w};
        __half ho[8];
#pragma unroll
        for (int i = 0; i < 8; ++i) {
            const float hv = acc[i] * rc + bb[i];
            ho[i] = __float2half(hv > 0.f ? hv : 0.f);     // bias + ReLU
        }
        *(uint4*)&out1h[(size_t)d * 128 + c * 8] = *(uint4*)ho;
    }
}

// ---------------------------------------------------------------------------
// Layer 2 GEMM via MFMA. 64 nodes/block, 4 waves; wave w owns the 16-node
// M-tile. A-frags are direct 16B loads of out1h (already fp16); B-frags
// scalar-load W2 (8KB, L2-hot) with packed cvts. Epilogue fuses a2 dots.
// ---------------------------------------------------------------------------
__global__ __launch_bounds__(256)
void k_gemm2m(const __half* __restrict__ out1h, const float* __restrict__ W2,
              const float* __restrict__ a_src2, const float* __restrict__ a_dst2,
              __half* __restrict__ xw2h, float* __restrict__ al2, float* __restrict__ ar2) {
    const int t = threadIdx.x;
    const int lane = t & 63;
    const int w = t >> 6;
    const int q = lane >> 4;
    const int n15 = lane & 15;
    const int n0 = (int)blockIdx.x * 64 + w * 16;
    const int ra = n0 + n15;
    const size_t rowA = (ra < N_NODES) ? (size_t)ra : (size_t)(N_NODES - 1);  // clamp tail

    f32x4 acc = {0.f, 0.f, 0.f, 0.f};
#pragma unroll
    for (int kt = 0; kt < 4; ++kt) {
        const int k0 = kt * 32 + q * 8;
        H8 A, B;
        A.v = *(const f16x8*)&out1h[rowA * 128 + k0];          // 16B, coalesced 32B runs/quad
        float wv[8];
#pragma unroll
        for (int i = 0; i < 8; ++i)
            wv[i] = W2[(size_t)(k0 + i) * 16 + n15];            // 64B runs, L2-hot
#pragma unroll
        for (int i = 0; i < 4; ++i)
            B.h2[i] = __float22half2_rn(make_float2(wv[2 * i], wv[2 * i + 1]));
        acc = __builtin_amdgcn_mfma_f32_16x16x32_f16(A.v, B.v, acc, 0, 0, 0);
    }

    // C/D: col j = n15, row m = q*4 + r. Fused attention dots (reduce over j).
    const float as = a_src2[n15], ad = a_dst2[n15];
#pragma unroll
    for (int r = 0; r < 4; ++r) {
        const int node = n0 + q * 4 + r;
        float ps = acc[r] * as;
        float pd = acc[r] * ad;
#pragma unroll
        for (int o = 1; o < 16; o <<= 1) {
            ps += __shfl_xor(ps, o, 64);
            pd += __shfl_xor(pd, o, 64);
        }
        if (node < N_NODES) {
            xw2h[(size_t)node * 16 + n15] = __float2half(acc[r]);  // 32B runs/quad
            if (n15 == 0) { al2[node] = ps; ar2[node] = pd; }
        }
    }
}

// ---------------------------------------------------------------------------
// Layer 2 pull-aggregation: one wave per node; R3: 32 edges in flight (was
// 16) — mean degree 17 completes in ONE memory round. Gathers are ~L2-hot
// (xw2h 3.2MB < 4MB/XCD) but still latency-bound.
// ---------------------------------------------------------------------------
__global__ __launch_bounds__(256)
void k_aggr2(const int* __restrict__ ssrc, const int* __restrict__ offs,
             const int* __restrict__ deg, const float* __restrict__ al2,
             const float* __restrict__ ar2, const __half* __restrict__ xw2h,
             const float* __restrict__ b2, float* __restrict__ out) {
    const int lane = threadIdx.x & 63;
    const int node = blockIdx.x * 4 + (threadIdx.x >> 6);
    const int j2 = lane & 7;                 // feature pair 2*j2, 2*j2+1
    const int eL = lane >> 3;                // 0..7
    const int beg = offs[node];
    const int n = deg[node];
    const float ard = ar2[node];
    float a0 = 0.f, a1 = 0.f, dnm = 0.f;
    for (int base = 0; base < n; base += 32) {
#pragma unroll
        for (int u = 0; u < 4; ++u) {
            const int e = base + u * 8 + eL;
            const bool p = e < n;
            const int s = ssrc[beg + (p ? e : 0)];
            float v = al2[s] + ard;
            v = v > 0.f ? v : NEG_SLOPE * v;
            const float w = p ? __expf(v) : 0.f;
            const float2 f = __half22float2(*(const __half2*)&xw2h[(size_t)s * 16 + j2 * 2]);
            a0 = fmaf(w, f.x, a0);
            a1 = fmaf(w, f.y, a1);
            dnm += w;
        }
    }
#pragma unroll
    for (int o = 8; o < 64; o <<= 1) {
        a0 += __shfl_xor(a0, o, 64);
        a1 += __shfl_xor(a1, o, 64);
        dnm += __shfl_xor(dnm, o, 64);
    }
    if (eL == 0) {
        out[(size_t)node * 16 + j2 * 2]     = a0 / dnm + b2[j2 * 2];
        out[(size_t)node * 16 + j2 * 2 + 1] = a1 / dnm + b2[j2 * 2 + 1];
    }
}

extern "C" void kernel_launch(void* const* d_in, const int* in_sizes, int n_in,
                              void* d_out, int out_size, void* d_ws, size_t ws_size,
                              hipStream_t stream) {
    const float* x      = (const float*)d_in[0];
    const int*   ei     = (const int*)d_in[1];
    const float* W1     = (const float*)d_in[2];
    const float* a_src1 = (const float*)d_in[3];
    const float* a_dst1 = (const float*)d_in[4];
    const float* b1     = (const float*)d_in[5];
    const float* W2     = (const float*)d_in[6];
    const float* a_src2 = (const float*)d_in[7];
    const float* a_dst2 = (const float*)d_in[8];
    const float* b2     = (const float*)d_in[9];
    float* out = (float*)d_out;

    // Workspace (byte-addressed). Aliases:
    //  - pairs (9.4MB packed) sits in out1h's region: consumed by k_fill3
    //    before k_aggr1 writes out1h.
    //  - xw2h/al2/ar2 sit in xw1h's region: written by k_gemm2m after k_aggr1
    //    is done with xw1h.
    char* wsb = (char*)d_ws;
    __half* xw1h = (__half*)wsb;                                  // N*128 half (25.6 MB)
    __half* xw2h = (__half*)wsb;                                  // N*16 half (alias)
    float*  al2  = (float*)(wsb + (size_t)N_NODES * 16 * 2);      // N fp32 (alias)
    float*  ar2  = al2 + N_NODES;                                 // N fp32 (alias)
    __half* out1h = (__half*)(wsb + (size_t)N_NODES * 128 * 2);   // N*128 half (25.6 MB)
    int*    pairs = (int*)out1h;                                  // 128*BSTRIDE int (alias, 9.4 MB)
    float*  al1  = (float*)(wsb + (size_t)N_NODES * 128 * 4);     // N*4 fp32
    float*  ar1  = al1 + (size_t)N_NODES * 4;                     // N*4
    int* ibcnt = (int*)(ar1 + (size_t)N_NODES * 4);               // 128 (zeroed)
    int* ioff  = ibcnt + 128;                                     // N
    int* ideg  = ioff + N_NODES;                                  // N
    int* isrc  = ideg + N_NODES;                                  // E_TOT

    hipMemsetAsync(ibcnt, 0, 128 * sizeof(int), stream);

    // Merged: MFMA layer-1 GEMM + edge bucket partition (independent roles).
    k_gemm1_part<<<NGEMM + NPART, 256, 0, stream>>>(x, W1, a_src1, a_dst1,
                                                    ei, ibcnt, pairs, xw1h, al1, ar1);
    // Per-bucket counting sort -> CSR (ioff/ideg/isrc).
    k_fill3<<<128, 1024, 0, stream>>>(pairs, ibcnt, ioff, ideg, isrc);

    // Layer 1 aggregation
    k_aggr1<<<N_NODES / 4, 256, 0, stream>>>(isrc, ioff, ideg, al1, ar1, xw1h, b1, out1h);

    // Layer 2 GEMM (MFMA) + fused attention dots
    k_gemm2m<<<(N_NODES + 63) / 64, 256, 0, stream>>>(out1h, W2, a_src2, a_dst2, xw2h, al2, ar2);

    // Layer 2 aggregation
    k_aggr2<<<N_NODES / 4, 256, 0, stream>>>(isrc, ioff, ideg, al2, ar2, xw2h, b2, out);
}

// Round 4
// 298.674 us; speedup vs baseline: 1.2165x; 1.0376x over previous
//
#include <hip/hip_runtime.h>
#include <hip/hip_fp16.h>

#define N_NODES 100000
#define N_EDGES 1600000
#define E_TOT   (N_EDGES + N_NODES)   // 1,700,000 incl. self-loops
#define NEG_SLOPE 0.2f
#define PART_EPB 4096                 // edges per partition block
#define BSTRIDE 18432                 // slots per bucket region (mean 17408 + 7.8 sigma)
#define NGEMM ((N_NODES + 63) / 64)   // 1563 gemm blocks (64 rows each)
#define NPART ((E_TOT + PART_EPB - 1) / PART_EPB)   // 416 partition blocks

using f16x8 = __attribute__((ext_vector_type(8))) _Float16;
using f32x4 = __attribute__((ext_vector_type(4))) float;
union H8 { f16x8 v; _Float16 h[8]; __half2 h2[4]; };
union H4 { __half2 h2[2]; uint2 u; };

// ---------------------------------------------------------------------------
// Merged kernel: blocks < NGEMM do the layer-1 GEMM via MFMA (fp16 in, fp32
// acc). Blocks >= NGEMM do the edge bucket-partition (zero data dependency
// between the roles -> one dispatch, overlapped).
//
// R4: GEMM role stages the 64-row x tile in LDS as fp16 ONCE per block
// (previously each of the 4 waves redundantly loaded + converted the same
// rows from global: 4x duplicated traffic and cvts). Row stride 136 halves
// (272B) -> ds_read_b128 A-frags are 2-way bank aliased = free (m136).
// M=64 also halves the per-node cost of the scalar W1 B-loads.
// ---------------------------------------------------------------------------
__global__ __launch_bounds__(256)
void k_gemm1_part(const float* __restrict__ x, const float* __restrict__ W1,
                  const float* __restrict__ a_src1, const float* __restrict__ a_dst1,
                  const int* __restrict__ ei, int* __restrict__ bcnt, int* __restrict__ pairs,
                  __half* __restrict__ xw1h, float* __restrict__ al1, float* __restrict__ ar1) {
    __shared__ int lcnt[128];
    __shared__ int lbase[128];
    __shared__ _Float16 sx[64][136];         // 17.4 KB; 272B row stride (see header)
    const int t = threadIdx.x;

    if (blockIdx.x >= NGEMM) {
        // ===== edge-partition role =====
        const int base = ((int)blockIdx.x - NGEMM) * PART_EPB;
        if (t < 128) lcnt[t] = 0;
        __syncthreads();
        int sr[16], dr[16];
#pragma unroll
        for (int u = 0; u < 16; ++u) {
            const int e = base + u * 256 + t;    // coalesced
            if (e < E_TOT) {
                int s, d;
                if (e < N_EDGES) { s = ei[e]; d = ei[N_EDGES + e]; }
                else             { s = d = e - N_EDGES; }
                sr[u] = s; dr[u] = d;
                atomicAdd(&lcnt[d >> 10], 1);    // LDS
            } else dr[u] = -1;
        }
        __syncthreads();
        if (t < 128) {
            const int c = lcnt[t];
            lbase[t] = (c > 0) ? atomicAdd(&bcnt[t], c) : 0;   // global, 1/bucket
            lcnt[t] = 0;
        }
        __syncthreads();
#pragma unroll
        for (int u = 0; u < 16; ++u) {
            if (dr[u] >= 0) {
                const int bk = dr[u] >> 10;
                const int r = atomicAdd(&lcnt[bk], 1);         // LDS
                pairs[(size_t)bk * BSTRIDE + lbase[bk] + r] = (sr[u] << 10) | (dr[u] & 1023);
            }
        }
        return;
    }

    // ===== MFMA GEMM role =====
    const int n0 = (int)blockIdx.x * 64;

    // Cooperative stage: 64 rows x 128 cols, f32 -> f16, coalesced float4.
    for (int i = t; i < 64 * 32; i += 256) {           // 8 iters/thread
        const int row = i >> 5;
        const int c4 = (i & 31) * 4;
        const int gr = n0 + row;
        const float4 xv = *(const float4*)&x[(size_t)(gr < N_NODES ? gr : N_NODES - 1) * 128 + c4];
        H4 tmp;
        tmp.h2[0] = __float22half2_rn(make_float2(xv.x, xv.y));
        tmp.h2[1] = __float22half2_rn(make_float2(xv.z, xv.w));
        *(uint2*)&sx[row][c4] = tmp.u;                 // 8B, 8B-aligned
    }
    __syncthreads();

    const int lane = t & 63;
    const int w = t >> 6;                    // wave id == head id
    const int q = lane >> 4;                 // quad
    const int n15 = lane & 15;
    const int j0 = (2 * w) * 16 + n15;       // col in tile 0 of this head
    const int j1 = (2 * w + 1) * 16 + n15;   // col in tile 1

    f32x4 acc[4][2] = {};                    // [m-group][n-tile]; all indices static

    for (int kt = 0; kt < 4; ++kt) {
        const int k0 = kt * 32 + q * 8;
        H8 A0, A1, A2, A3, B0, B1;
        A0.v = *(const f16x8*)&sx[n15][k0];            // 16B ds_read_b128
        A1.v = *(const f16x8*)&sx[16 + n15][k0];
        A2.v = *(const f16x8*)&sx[32 + n15][k0];
        A3.v = *(const f16x8*)&sx[48 + n15][k0];
        {
            float w0[8], w1[8];
#pragma unroll
            for (int i = 0; i < 8; ++i) {
                w0[i] = W1[(size_t)(k0 + i) * 128 + j0];   // 64B runs, L2-hot
                w1[i] = W1[(size_t)(k0 + i) * 128 + j1];
            }
#pragma unroll
            for (int i = 0; i < 4; ++i) {
                B0.h2[i] = __float22half2_rn(make_float2(w0[2 * i], w0[2 * i + 1]));
                B1.h2[i] = __float22half2_rn(make_float2(w1[2 * i], w1[2 * i + 1]));
            }
        }
        acc[0][0] = __builtin_amdgcn_mfma_f32_16x16x32_f16(A0.v, B0.v, acc[0][0], 0, 0, 0);
        acc[0][1] = __builtin_amdgcn_mfma_f32_16x16x32_f16(A0.v, B1.v, acc[0][1], 0, 0, 0);
        acc[1][0] = __builtin_amdgcn_mfma_f32_16x16x32_f16(A1.v, B0.v, acc[1][0], 0, 0, 0);
        acc[1][1] = __builtin_amdgcn_mfma_f32_16x16x32_f16(A1.v, B1.v, acc[1][1], 0, 0, 0);
        acc[2][0] = __builtin_amdgcn_mfma_f32_16x16x32_f16(A2.v, B0.v, acc[2][0], 0, 0, 0);
        acc[2][1] = __builtin_amdgcn_mfma_f32_16x16x32_f16(A2.v, B1.v, acc[2][1], 0, 0, 0);
        acc[3][0] = __builtin_amdgcn_mfma_f32_16x16x32_f16(A3.v, B0.v, acc[3][0], 0, 0, 0);
        acc[3][1] = __builtin_amdgcn_mfma_f32_16x16x32_f16(A3.v, B1.v, acc[3][1], 0, 0, 0);
    }

    // Epilogue: D col = n15-based j, row m-group*16 + q*4 + r. Fused attn dots.
    const float as0 = a_src1[j0], as1 = a_src1[j1];
    const float ad0 = a_dst1[j0], ad1 = a_dst1[j1];
#pragma unroll
    for (int m = 0; m < 4; ++m) {
#pragma unroll
        for (int r = 0; r < 4; ++r) {
            const int node = n0 + m * 16 + q * 4 + r;
            const float vA = acc[m][0][r], vB = acc[m][1][r];
            const bool ok = node < N_NODES;
            if (ok) {
                xw1h[(size_t)node * 128 + j0] = __float2half(vA);   // 32B runs/quad
                xw1h[(size_t)node * 128 + j1] = __float2half(vB);
            }
            float ps = vA * as0 + vB * as1;
            float pd = vA * ad0 + vB * ad1;
#pragma unroll
            for (int o = 1; o < 16; o <<= 1) {   // reduce over the 16 j-lanes (quad preserved)
                ps += __shfl_xor(ps, o, 64);
                pd += __shfl_xor(pd, o, 64);
            }
            if (n15 == 0 && ok) {
                al1[(size_t)node * 4 + w] = ps;
                ar1[(size_t)node * 4 + w] = pd;
            }
        }
    }
}

// ---------------------------------------------------------------------------
// k_fill3: one 1024-thread block per bucket. Per-bucket counting sort with
// LDS histogram + LDS cursors — zero global atomics. Also emits ioff/deg.
// sbase: bcnt staged cooperatively into LDS then summed from LDS.
// ---------------------------------------------------------------------------
__global__ __launch_bounds__(1024)
void k_fill3(const int* __restrict__ pairs, const int* __restrict__ bcnt,
             int* __restrict__ ioff, int* __restrict__ deg, int* __restrict__ ssrc) {
    const int bucket = blockIdx.x;
    const int t = threadIdx.x;
    const int cnt = bcnt[bucket];
    __shared__ int lhist[1024];
    __shared__ int lcur[1024];
    __shared__ int wsum[16];
    __shared__ int sbc[128];
    __shared__ int sbase;
    lhist[t] = 0;
    if (t < 128) sbc[t] = bcnt[t];           // coalesced, parallel
    __syncthreads();
    if (t == 0) {                            // sum lower buckets from LDS (pipelined)
        int b = 0;
        for (int k = 0; k < bucket; ++k) b += sbc[k];
        sbase = b;
    }
    for (int i = t; i < cnt; i += 1024) {
        const int p = pairs[(size_t)bucket * BSTRIDE + i];
        atomicAdd(&lhist[p & 1023], 1);
    }
    __syncthreads();
    const int v = lhist[t];
    int inc = v;
    const int lane = t & 63, wid = t >> 6;
#pragma unroll
    for (int o = 1; o < 64; o <<= 1) {
        const int nv = __shfl_up(inc, o, 64);
        if (lane >= o) inc += nv;
    }
    if (lane == 63) wsum[wid] = inc;
    __syncthreads();
    if (t == 0) {
        int acc = 0;
#pragma unroll
        for (int k = 0; k < 16; ++k) { const int tv = wsum[k]; wsum[k] = acc; acc += tv; }
    }
    __syncthreads();
    const int gofs = sbase + (inc - v) + wsum[wid];   // global CSR offset of node d
    const int d = bucket * 1024 + t;
    if (d < N_NODES) { ioff[d] = gofs; deg[d] = v; }
    lcur[t] = gofs;
    __syncthreads();
    for (int i = t; i < cnt; i += 1024) {
        const int p = pairs[(size_t)bucket * BSTRIDE + i];
        const int pos = atomicAdd(&lcur[p & 1023], 1);     // LDS
        ssrc[pos] = p >> 10;
    }
}

// ---------------------------------------------------------------------------
// Layer 1 pull-aggregation (VGPR 20 — do NOT preload epilogue state, R10;
// do NOT fuse layer-2 GEMM here, R1; do NOT widen MLP, R3: 16-in-flight
// measured identical to 8 -> per-CU miss-queue bound, not per-wave MLP).
// One wave per dst node, zero barriers; uint4 gathers, 8 edges in flight.
// ---------------------------------------------------------------------------
__global__ __launch_bounds__(256)
void k_aggr1(const int* __restrict__ ssrc, const int* __restrict__ offs,
             const int* __restrict__ deg, const float* __restrict__ al1,
             const float* __restrict__ ar1, const __half* __restrict__ xw1h,
             const float* __restrict__ b1, __half* __restrict__ out1h) {
    const int lane = threadIdx.x & 63;
    const int d = blockIdx.x * 4 + (threadIdx.x >> 6);
    const int g = lane >> 4;                 // edge group 0..3
    const int c = lane & 15;                 // col group: features 8c..8c+7
    const int h = c >> 2;                    // head of this col group
    const int beg = offs[d];
    const int n = deg[d];
    const float arh = ar1[(size_t)d * 4 + h];
    float acc[8] = {0.f, 0.f, 0.f, 0.f, 0.f, 0.f, 0.f, 0.f};
    float dnm = 0.f;

    for (int base = 0; base < n; base += 8) {
#pragma unroll
        for (int u = 0; u < 2; ++u) {
            const int e = base + u * 4 + g;
            const bool p = e < n;
            const int s = ssrc[beg + (p ? e : 0)];         // L1-hot (sequential)
            float v = al1[(size_t)s * 4 + h] + arh;        // broadcast gather
            v = v > 0.f ? v : NEG_SLOPE * v;
            const float w = p ? __expf(v) : 0.f;
            const uint4 rv = *(const uint4*)&xw1h[(size_t)s * 128 + c * 8];
            const float2 f0 = __half22float2(*(const __half2*)&rv.x);
            const float2 f1 = __half22float2(*(const __half2*)&rv.y);
            const float2 f2 = __half22float2(*(const __half2*)&rv.z);
            const float2 f3 = __half22float2(*(const __half2*)&rv.w);
            acc[0] = fmaf(w, f0.x, acc[0]); acc[1] = fmaf(w, f0.y, acc[1]);
            acc[2] = fmaf(w, f1.x, acc[2]); acc[3] = fmaf(w, f1.y, acc[3]);
            acc[4] = fmaf(w, f2.x, acc[4]); acc[5] = fmaf(w, f2.y, acc[5]);
            acc[6] = fmaf(w, f3.x, acc[6]); acc[7] = fmaf(w, f3.y, acc[7]);
            dnm += w;
        }
    }
#pragma unroll
    for (int i = 0; i < 8; ++i) {
        acc[i] += __shfl_xor(acc[i], 16, 64);
        acc[i] += __shfl_xor(acc[i], 32, 64);
    }
    dnm += __shfl_xor(dnm, 16, 64);
    dnm += __shfl_xor(dnm, 32, 64);
    if (g == 0) {
        const float rc = 1.f / dnm;
        const float4 b01 = *(const float4*)&b1[c * 8];
        const float4 b23 = *(const float4*)&b1[c * 8 + 4];
        const float bb[8] = {b01.x, b01.y, b01.z, b01.w, b23.x, b23.y, b23.z, b23.w};
        __half ho[8];
#pragma unroll
        for (int i = 0; i < 8; ++i) {
            const float hv = acc[i] * rc + bb[i];
            ho[i] = __float2half(hv > 0.f ? hv : 0.f);     // bias + ReLU
        }
        *(uint4*)&out1h[(size_t)d * 128 + c * 8] = *(uint4*)ho;
    }
}

// ---------------------------------------------------------------------------
// Layer 2 GEMM via MFMA. R4: 128 nodes/block, 4 waves; wave w owns TWO
// 16-node M-tiles (rows n0+n15 and n0+64+n15) -> W2 scalar-loads + cvts
// amortized over 2x the rows. A-frags are direct 16B loads of out1h.
// ---------------------------------------------------------------------------
__global__ __launch_bounds__(256)
void k_gemm2m(const __half* __restrict__ out1h, const float* __restrict__ W2,
              const float* __restrict__ a_src2, const float* __restrict__ a_dst2,
              __half* __restrict__ xw2h, float* __restrict__ al2, float* __restrict__ ar2) {
    const int t = threadIdx.x;
    const int lane = t & 63;
    const int w = t >> 6;
    const int q = lane >> 4;
    const int n15 = lane & 15;
    const int n0 = (int)blockIdx.x * 128 + w * 16;
    const int ra0 = n0 + n15;
    const int ra1 = n0 + 64 + n15;
    const size_t rowA0 = (ra0 < N_NODES) ? (size_t)ra0 : (size_t)(N_NODES - 1);
    const size_t rowA1 = (ra1 < N_NODES) ? (size_t)ra1 : (size_t)(N_NODES - 1);

    f32x4 acc0 = {0.f, 0.f, 0.f, 0.f}, acc1 = acc0;
#pragma unroll
    for (int kt = 0; kt < 4; ++kt) {
        const int k0 = kt * 32 + q * 8;
        H8 A0, A1, B;
        A0.v = *(const f16x8*)&out1h[rowA0 * 128 + k0];    // 16B, 32B runs/quad
        A1.v = *(const f16x8*)&out1h[rowA1 * 128 + k0];
        float wv[8];
#pragma unroll
        for (int i = 0; i < 8; ++i)
            wv[i] = W2[(size_t)(k0 + i) * 16 + n15];        // 64B runs, L1-hot
#pragma unroll
        for (int i = 0; i < 4; ++i)
            B.h2[i] = __float22half2_rn(make_float2(wv[2 * i], wv[2 * i + 1]));
        acc0 = __builtin_amdgcn_mfma_f32_16x16x32_f16(A0.v, B.v, acc0, 0, 0, 0);
        acc1 = __builtin_amdgcn_mfma_f32_16x16x32_f16(A1.v, B.v, acc1, 0, 0, 0);
    }

    // C/D: col j = n15, row m = q*4 + r. Fused attention dots (reduce over j).
    const float as = a_src2[n15], ad = a_dst2[n15];
#pragma unroll
    for (int m = 0; m < 2; ++m) {
        const f32x4 acc = m ? acc1 : acc0;
#pragma unroll
        for (int r = 0; r < 4; ++r) {
            const int node = n0 + m * 64 + q * 4 + r;
            float ps = acc[r] * as;
            float pd = acc[r] * ad;
#pragma unroll
            for (int o = 1; o < 16; o <<= 1) {
                ps += __shfl_xor(ps, o, 64);
                pd += __shfl_xor(pd, o, 64);
            }
            if (node < N_NODES) {
                xw2h[(size_t)node * 16 + n15] = __float2half(acc[r]);  // 32B runs/quad
                if (n15 == 0) { al2[node] = ps; ar2[node] = pd; }
            }
        }
    }
}

// ---------------------------------------------------------------------------
// Layer 2 pull-aggregation: one wave per node; 32 edges in flight — mean
// degree 17 completes in ONE memory round (xw2h 3.2MB ~L2-resident).
// ---------------------------------------------------------------------------
__global__ __launch_bounds__(256)
void k_aggr2(const int* __restrict__ ssrc, const int* __restrict__ offs,
             const int* __restrict__ deg, const float* __restrict__ al2,
             const float* __restrict__ ar2, const __half* __restrict__ xw2h,
             const float* __restrict__ b2, float* __restrict__ out) {
    const int lane = threadIdx.x & 63;
    const int node = blockIdx.x * 4 + (threadIdx.x >> 6);
    const int j2 = lane & 7;                 // feature pair 2*j2, 2*j2+1
    const int eL = lane >> 3;                // 0..7
    const int beg = offs[node];
    const int n = deg[node];
    const float ard = ar2[node];
    float a0 = 0.f, a1 = 0.f, dnm = 0.f;
    for (int base = 0; base < n; base += 32) {
#pragma unroll
        for (int u = 0; u < 4; ++u) {
            const int e = base + u * 8 + eL;
            const bool p = e < n;
            const int s = ssrc[beg + (p ? e : 0)];
            float v = al2[s] + ard;
            v = v > 0.f ? v : NEG_SLOPE * v;
            const float w = p ? __expf(v) : 0.f;
            const float2 f = __half22float2(*(const __half2*)&xw2h[(size_t)s * 16 + j2 * 2]);
            a0 = fmaf(w, f.x, a0);
            a1 = fmaf(w, f.y, a1);
            dnm += w;
        }
    }
#pragma unroll
    for (int o = 8; o < 64; o <<= 1) {
        a0 += __shfl_xor(a0, o, 64);
        a1 += __shfl_xor(a1, o, 64);
        dnm += __shfl_xor(dnm, o, 64);
    }
    if (eL == 0) {
        out[(size_t)node * 16 + j2 * 2]     = a0 / dnm + b2[j2 * 2];
        out[(size_t)node * 16 + j2 * 2 + 1] = a1 / dnm + b2[j2 * 2 + 1];
    }
}

extern "C" void kernel_launch(void* const* d_in, const int* in_sizes, int n_in,
                              void* d_out, int out_size, void* d_ws, size_t ws_size,
                              hipStream_t stream) {
    const float* x      = (const float*)d_in[0];
    const int*   ei     = (const int*)d_in[1];
    const float* W1     = (const float*)d_in[2];
    const float* a_src1 = (const float*)d_in[3];
    const float* a_dst1 = (const float*)d_in[4];
    const float* b1     = (const float*)d_in[5];
    const float* W2     = (const float*)d_in[6];
    const float* a_src2 = (const float*)d_in[7];
    const float* a_dst2 = (const float*)d_in[8];
    const float* b2     = (const float*)d_in[9];
    float* out = (float*)d_out;

    // Workspace (byte-addressed). Aliases:
    //  - pairs (9.4MB packed) sits in out1h's region: consumed by k_fill3
    //    before k_aggr1 writes out1h.
    //  - xw2h/al2/ar2 sit in xw1h's region: written by k_gemm2m after k_aggr1
    //    is done with xw1h.
    char* wsb = (char*)d_ws;
    __half* xw1h = (__half*)wsb;                                  // N*128 half (25.6 MB)
    __half* xw2h = (__half*)wsb;                                  // N*16 half (alias)
    float*  al2  = (float*)(wsb + (size_t)N_NODES * 16 * 2);      // N fp32 (alias)
    float*  ar2  = al2 + N_NODES;                                 // N fp32 (alias)
    __half* out1h = (__half*)(wsb + (size_t)N_NODES * 128 * 2);   // N*128 half (25.6 MB)
    int*    pairs = (int*)out1h;                                  // 128*BSTRIDE int (alias, 9.4 MB)
    float*  al1  = (float*)(wsb + (size_t)N_NODES * 128 * 4);     // N*4 fp32
    float*  ar1  = al1 + (size_t)N_NODES * 4;                     // N*4
    int* ibcnt = (int*)(ar1 + (size_t)N_NODES * 4);               // 128 (zeroed)
    int* ioff  = ibcnt + 128;                                     // N
    int* ideg  = ioff + N_NODES;                                  // N
    int* isrc  = ideg + N_NODES;                                  // E_TOT

    hipMemsetAsync(ibcnt, 0, 128 * sizeof(int), stream);

    // Merged: MFMA layer-1 GEMM (staged-x, M=64) + edge bucket partition.
    k_gemm1_part<<<NGEMM + NPART, 256, 0, stream>>>(x, W1, a_src1, a_dst1,
                                                    ei, ibcnt, pairs, xw1h, al1, ar1);
    // Per-bucket counting sort -> CSR (ioff/ideg/isrc).
    k_fill3<<<128, 1024, 0, stream>>>(pairs, ibcnt, ioff, ideg, isrc);

    // Layer 1 aggregation
    k_aggr1<<<N_NODES / 4, 256, 0, stream>>>(isrc, ioff, ideg, al1, ar1, xw1h, b1, out1h);

    // Layer 2 GEMM (MFMA, 2 M-tiles/wave) + fused attention dots
    k_gemm2m<<<(N_NODES + 127) / 128, 256, 0, stream>>>(out1h, W2, a_src2, a_dst2, xw2h, al2, ar2);

    // Layer 2 aggregation
    k_aggr2<<<N_NODES / 4, 256, 0, stream>>>(isrc, ioff, ideg, al2, ar2, xw2h, b2, out);
}